// Round 1
// baseline (2483.056 us; speedup 1.0000x reference)
//
#include <hip/hip_runtime.h>
#include <math.h>

#define HIDDEN 16
#define CIN 5
#define CH_ALL 21   // CIN + HIDDEN
#define BB 8
#define TT 12
#define HH 256
#define WW 256
#define KK 189      // CH_ALL * 9
#define OC 64       // 4 * HIDDEN

#define TX 32
#define TY 8
#define HALO_X (TX + 2)
#define HALO_Y (TY + 2)

__device__ __forceinline__ float fast_sigmoid(float x) {
    return 1.0f / (1.0f + __expf(-x));
}

__device__ __forceinline__ float fast_tanh(float x) {
    float e2 = __expf(-2.0f * fabsf(x));
    float t = (1.0f - e2) / (1.0f + e2);
    return copysignf(t, x);
}

// Transpose W_cell [64][21][3][3] (OIHW, flattened o*189+k) -> Wt [189][64]
__global__ void transpose_w_kernel(const float* __restrict__ Wc,
                                   float* __restrict__ Wt) {
    int i = blockIdx.x * 256 + threadIdx.x;
    if (i < KK * OC) {
        int o = i / KK;
        int k = i - o * KK;
        Wt[k * OC + o] = Wc[i];
    }
}

// One ConvLSTM time step, fused: conv(concat(x_t, h_in)) + bias -> gates -> h/c update
__global__ __launch_bounds__(TX * TY)
void convlstm_step_kernel(const float* __restrict__ x,   // [B][T][CIN][H][W]
                          int t,
                          const float* __restrict__ h_in,
                          float* __restrict__ h_out,
                          float* __restrict__ c_state,   // in-place (pointwise)
                          const float* __restrict__ Wt,  // [189][64]
                          const float* __restrict__ bias,// [64]
                          int first) {
    __shared__ float tile[CH_ALL][HALO_Y][HALO_X];

    const int bx = blockIdx.x;   // WW/TX tiles
    const int by = blockIdx.y;   // HH/TY tiles
    const int bb = blockIdx.z;   // batch
    const int tx = threadIdx.x;
    const int ty = threadIdx.y;
    const int tid = ty * TX + tx;
    const int x0 = bx * TX;
    const int y0 = by * TY;

    // ---- stage x_t and h_in tile (with halo, zero-padded) into LDS ----
    const int TOT = CH_ALL * HALO_Y * HALO_X;  // 21*10*34 = 7140
    for (int e = tid; e < TOT; e += TX * TY) {
        int ci  = e / (HALO_Y * HALO_X);
        int rem = e - ci * (HALO_Y * HALO_X);
        int ly  = rem / HALO_X;
        int lx  = rem - ly * HALO_X;
        int gy = y0 + ly - 1;
        int gx = x0 + lx - 1;
        float v = 0.0f;
        if (gy >= 0 && gy < HH && gx >= 0 && gx < WW) {
            if (ci < CIN) {
                v = x[(((size_t)bb * TT + t) * CIN + ci) * (size_t)(HH * WW)
                      + (size_t)gy * WW + gx];
            } else if (!first) {
                v = h_in[((size_t)bb * HIDDEN + (ci - CIN)) * (size_t)(HH * WW)
                         + (size_t)gy * WW + gx];
            }
        }
        tile[ci][ly][lx] = v;
    }
    __syncthreads();

    // ---- conv: 64 accumulators per thread, weights via uniform scalar loads ----
    float acc[OC];
    #pragma unroll
    for (int o = 0; o < OC; ++o) acc[o] = 0.0f;

    #pragma unroll 1
    for (int ci = 0; ci < CH_ALL; ++ci) {
        #pragma unroll
        for (int ky = 0; ky < 3; ++ky) {
            #pragma unroll
            for (int kx = 0; kx < 3; ++kx) {
                float v = tile[ci][ty + ky][tx + kx];
                const float* __restrict__ wk = Wt + ((ci * 3 + ky) * 3 + kx) * OC;
                #pragma unroll
                for (int o = 0; o < OC; ++o) {
                    acc[o] = fmaf(wk[o], v, acc[o]);
                }
            }
        }
    }

    // ---- gates + state update ----
    const int py = y0 + ty;
    const int px = x0 + tx;
    const size_t pix = (size_t)py * WW + px;

    #pragma unroll
    for (int u = 0; u < HIDDEN; ++u) {
        float pre_i = acc[u]          + bias[u];
        float pre_f = acc[u + 16]     + bias[u + 16];
        float pre_o = acc[u + 32]     + bias[u + 32];
        float pre_g = acc[u + 48]     + bias[u + 48];

        float ig = fast_sigmoid(pre_i);
        float fg = fast_sigmoid(pre_f);
        float og = fast_sigmoid(pre_o);
        float gg = fast_tanh(pre_g);

        size_t idx = ((size_t)bb * HIDDEN + u) * (size_t)(HH * WW) + pix;
        float c_old = first ? 0.0f : c_state[idx];
        float c_new = fg * c_old + ig * gg;
        c_state[idx] = c_new;
        h_out[idx] = og * fast_tanh(c_new);
    }
}

// Final 1x1 conv: out[b][y][x] = b_final + sum_u W_final[u] * h[b][u][y][x]
__global__ void final_conv_kernel(const float* __restrict__ h,
                                  const float* __restrict__ Wf,   // [16]
                                  const float* __restrict__ bf,   // [1]
                                  float* __restrict__ out) {
    int i = blockIdx.x * 256 + threadIdx.x;
    if (i >= BB * HH * WW) return;
    int bb  = i / (HH * WW);
    int pix = i - bb * (HH * WW);
    float s = bf[0];
    #pragma unroll
    for (int u = 0; u < HIDDEN; ++u) {
        s += Wf[u] * h[((size_t)bb * HIDDEN + u) * (size_t)(HH * WW) + pix];
    }
    out[i] = s;
}

extern "C" void kernel_launch(void* const* d_in, const int* in_sizes, int n_in,
                              void* d_out, int out_size, void* d_ws, size_t ws_size,
                              hipStream_t stream) {
    const float* x  = (const float*)d_in[0];  // [8][12][5][256][256]
    const float* Wc = (const float*)d_in[1];  // [64][21][3][3]
    const float* bc = (const float*)d_in[2];  // [64]
    const float* Wf = (const float*)d_in[3];  // [1][16][1][1]
    const float* bf = (const float*)d_in[4];  // [1]
    float* out = (float*)d_out;               // [8][1][256][256]

    char* ws = (char*)d_ws;
    const size_t state_bytes = (size_t)BB * HIDDEN * HH * WW * sizeof(float); // 33.55 MB
    float* h_a = (float*)(ws);
    float* h_b = (float*)(ws + state_bytes);
    float* c   = (float*)(ws + 2 * state_bytes);
    float* Wt  = (float*)(ws + 3 * state_bytes);   // 48.4 KB

    transpose_w_kernel<<<(KK * OC + 255) / 256, 256, 0, stream>>>(Wc, Wt);

    dim3 grid(WW / TX, HH / TY, BB);   // 8 x 32 x 8 = 2048 blocks
    dim3 block(TX, TY, 1);             // 256 threads

    const float* h_in = h_a;   // unused on first step
    for (int t = 0; t < TT; ++t) {
        float* h_out = (t & 1) ? h_b : h_a;
        convlstm_step_kernel<<<grid, block, 0, stream>>>(
            x, t, h_in, h_out, c, Wt, bc, (t == 0) ? 1 : 0);
        h_in = h_out;
    }

    final_conv_kernel<<<(BB * HH * WW + 255) / 256, 256, 0, stream>>>(
        h_in, Wf, bf, out);
}

// Round 2
// 1981.721 us; speedup vs baseline: 1.2530x; 1.2530x over previous
//
#include <hip/hip_runtime.h>
#include <math.h>

#define HIDDEN 16
#define CIN 5
#define CH_ALL 21   // CIN + HIDDEN
#define BB 8
#define TT 12
#define HH 256
#define WW 256
#define KK 189      // CH_ALL * 9
#define OC 64       // 4 * HIDDEN

#define TX 32
#define TY 8
#define HALO_X (TX + 2)
#define HALO_Y (TY + 2)

__device__ __forceinline__ float fast_sigmoid(float x) {
    return 1.0f / (1.0f + __expf(-x));
}

__device__ __forceinline__ float fast_tanh(float x) {
    float e2 = __expf(-2.0f * fabsf(x));
    float t = (1.0f - e2) / (1.0f + e2);
    return copysignf(t, x);
}

// Transpose W_cell [64][21][3][3] (OIHW, o = g*16+u, k = ci*9+ky*3+kx)
// -> Wt [189][64] with inner order u*4+g (gate-interleaved per hidden unit),
// so pass p (u in [4p,4p+4)) reads 16 contiguous floats per tap.
__global__ void transpose_w_kernel(const float* __restrict__ Wc,
                                   float* __restrict__ Wt) {
    int i = blockIdx.x * 256 + threadIdx.x;
    if (i < KK * OC) {
        int o = i / KK;
        int k = i - o * KK;
        int u = o & 15;
        int g = o >> 4;
        Wt[k * OC + u * 4 + g] = Wc[i];
    }
}

// One ConvLSTM time step, fused: conv(concat(x_t, h_in)) + bias -> gates -> h/c.
// 4 passes of 16 accumulators each to keep VGPR pressure low (avoid AGPR
// round-trips that ate ~half the VALU issue in R1).
__global__ __launch_bounds__(TX * TY, 4)
void convlstm_step_kernel(const float* __restrict__ x,   // [B][T][CIN][H][W]
                          int t,
                          const float* __restrict__ h_in,
                          float* __restrict__ h_out,
                          float* __restrict__ c_state,   // in-place (pointwise)
                          const float* __restrict__ Wt,  // [189][64] gate-interleaved
                          const float* __restrict__ bias,// [64]
                          int first) {
    __shared__ float tile[CH_ALL][HALO_Y][HALO_X];

    const int bx = blockIdx.x;
    const int by = blockIdx.y;
    const int bb = blockIdx.z;
    const int tx = threadIdx.x;
    const int ty = threadIdx.y;
    const int tid = ty * TX + tx;
    const int x0 = bx * TX;
    const int y0 = by * TY;

    // ---- stage x_t and h_in tile (with halo, zero-padded) into LDS ----
    const int TOT = CH_ALL * HALO_Y * HALO_X;  // 7140
    for (int e = tid; e < TOT; e += TX * TY) {
        int ci  = e / (HALO_Y * HALO_X);
        int rem = e - ci * (HALO_Y * HALO_X);
        int ly  = rem / HALO_X;
        int lx  = rem - ly * HALO_X;
        int gy = y0 + ly - 1;
        int gx = x0 + lx - 1;
        float v = 0.0f;
        if (gy >= 0 && gy < HH && gx >= 0 && gx < WW) {
            if (ci < CIN) {
                v = x[(((size_t)bb * TT + t) * CIN + ci) * (size_t)(HH * WW)
                      + (size_t)gy * WW + gx];
            } else if (!first) {
                v = h_in[((size_t)bb * HIDDEN + (ci - CIN)) * (size_t)(HH * WW)
                         + (size_t)gy * WW + gx];
            }
        }
        tile[ci][ly][lx] = v;
    }
    __syncthreads();

    const int py = y0 + ty;
    const int px = x0 + tx;
    const size_t pix = (size_t)py * WW + px;

    // ---- 4 passes; pass p handles hidden units u in [4p, 4p+4), all 4 gates ----
    #pragma unroll 1
    for (int p = 0; p < 4; ++p) {
        // acc[j*4+g] = pre-activation of gate g, unit u = 4p+j. Init with bias.
        float acc[16];
        #pragma unroll
        for (int j = 0; j < 4; ++j) {
            #pragma unroll
            for (int g = 0; g < 4; ++g) {
                acc[j * 4 + g] = bias[g * 16 + p * 4 + j];
            }
        }

        #pragma unroll 1
        for (int ci = 0; ci < CH_ALL; ++ci) {
            #pragma unroll
            for (int ky = 0; ky < 3; ++ky) {
                #pragma unroll
                for (int kx = 0; kx < 3; ++kx) {
                    float v = tile[ci][ty + ky][tx + kx];
                    const float* __restrict__ wk =
                        Wt + ((ci * 3 + ky) * 3 + kx) * OC + p * 16;
                    #pragma unroll
                    for (int j = 0; j < 16; ++j) {
                        acc[j] = fmaf(wk[j], v, acc[j]);
                    }
                }
            }
        }

        // ---- gates + state update for these 4 hidden units ----
        #pragma unroll
        for (int j = 0; j < 4; ++j) {
            int u = p * 4 + j;
            float ig = fast_sigmoid(acc[j * 4 + 0]);
            float fg = fast_sigmoid(acc[j * 4 + 1]);
            float og = fast_sigmoid(acc[j * 4 + 2]);
            float gg = fast_tanh(acc[j * 4 + 3]);

            size_t idx = ((size_t)bb * HIDDEN + u) * (size_t)(HH * WW) + pix;
            float c_old = first ? 0.0f : c_state[idx];
            float c_new = fg * c_old + ig * gg;
            c_state[idx] = c_new;
            h_out[idx] = og * fast_tanh(c_new);
        }
    }
}

// Final 1x1 conv
__global__ void final_conv_kernel(const float* __restrict__ h,
                                  const float* __restrict__ Wf,   // [16]
                                  const float* __restrict__ bf,   // [1]
                                  float* __restrict__ out) {
    int i = blockIdx.x * 256 + threadIdx.x;
    if (i >= BB * HH * WW) return;
    int bb  = i / (HH * WW);
    int pix = i - bb * (HH * WW);
    float s = bf[0];
    #pragma unroll
    for (int u = 0; u < HIDDEN; ++u) {
        s += Wf[u] * h[((size_t)bb * HIDDEN + u) * (size_t)(HH * WW) + pix];
    }
    out[i] = s;
}

extern "C" void kernel_launch(void* const* d_in, const int* in_sizes, int n_in,
                              void* d_out, int out_size, void* d_ws, size_t ws_size,
                              hipStream_t stream) {
    const float* x  = (const float*)d_in[0];  // [8][12][5][256][256]
    const float* Wc = (const float*)d_in[1];  // [64][21][3][3]
    const float* bc = (const float*)d_in[2];  // [64]
    const float* Wf = (const float*)d_in[3];  // [1][16][1][1]
    const float* bf = (const float*)d_in[4];  // [1]
    float* out = (float*)d_out;               // [8][1][256][256]

    char* ws = (char*)d_ws;
    const size_t state_bytes = (size_t)BB * HIDDEN * HH * WW * sizeof(float);
    float* h_a = (float*)(ws);
    float* h_b = (float*)(ws + state_bytes);
    float* c   = (float*)(ws + 2 * state_bytes);
    float* Wt  = (float*)(ws + 3 * state_bytes);

    transpose_w_kernel<<<(KK * OC + 255) / 256, 256, 0, stream>>>(Wc, Wt);

    dim3 grid(WW / TX, HH / TY, BB);   // 2048 blocks
    dim3 block(TX, TY, 1);             // 256 threads

    const float* h_in = h_a;
    for (int t = 0; t < TT; ++t) {
        float* h_out = (t & 1) ? h_b : h_a;
        convlstm_step_kernel<<<grid, block, 0, stream>>>(
            x, t, h_in, h_out, c, Wt, bc, (t == 0) ? 1 : 0);
        h_in = h_out;
    }

    final_conv_kernel<<<(BB * HH * WW + 255) / 256, 256, 0, stream>>>(
        h_in, Wf, bf, out);
}

// Round 3
// 781.428 us; speedup vs baseline: 3.1776x; 2.5360x over previous
//
#include <hip/hip_runtime.h>
#include <math.h>

#define HIDDEN 16
#define CIN 5
#define BB 8
#define TT 12
#define HH 256
#define WW 256
#define KPAD 32          // 21 real k-channels (16 h + 5 x) padded to 32
#define TX 32
#define TY 8
#define HALO_X 34
#define HALO_Y 10
#define NPX (HALO_X * HALO_Y)   // 340 staged pixels

typedef __attribute__((ext_vector_type(8))) short bf16x8;   // 8 bf16 (4 VGPRs)
typedef __attribute__((ext_vector_type(4))) float floatx4;

__device__ __forceinline__ unsigned short f2bf(float f) {   // RNE fp32->bf16
    unsigned int u = __float_as_uint(f);
    u += 0x7fffu + ((u >> 16) & 1u);
    return (unsigned short)(u >> 16);
}
__device__ __forceinline__ float bf2f(unsigned short s) {
    return __uint_as_float(((unsigned int)s) << 16);
}
__device__ __forceinline__ float fast_sigmoid(float x) { return 1.0f / (1.0f + __expf(-x)); }
__device__ __forceinline__ float fast_tanh(float x) {
    float e2 = __expf(-2.0f * fabsf(x));
    float t = (1.0f - e2) / (1.0f + e2);
    return copysignf(t, x);
}

// Pack W_cell [64][21][3][3] into exact B-fragment layout for
// mfma_f32_16x16x32_bf16: Wfrag[tap][gate][lane][j], where lane holds
// B[k=(lane>>4)*8+j][col=lane&15], col = hidden unit u, N-tile = gate.
// k-order: 0..15 = h units (ci_ref 5+k), 16..20 = x chans (ci_ref k-16), 21..31 = 0.
__global__ void prep_kernel(const float* __restrict__ Wc,
                            unsigned short* __restrict__ Wfrag) {
    int i = blockIdx.x * 256 + threadIdx.x;
    if (i >= 9 * 4 * 64 * 8) return;
    int j    = i & 7;
    int lane = (i >> 3) & 63;
    int g    = (i >> 9) & 3;
    int tap  = i >> 11;
    int k    = ((lane >> 4) << 3) + j;
    int col  = lane & 15;
    int o    = g * 16 + col;          // reference outch = gate*16 + unit
    float w  = 0.0f;
    if (k < 21) {
        int ci_ref = (k < 16) ? (5 + k) : (k - 16);
        w = Wc[(o * 21 + ci_ref) * 9 + tap];
    }
    Wfrag[i] = f2bf(w);
}

// One ConvLSTM step: implicit-GEMM conv via MFMA + fused gates/state update.
// h layout: bf16 channel-last [b][y][x][16]; c: fp32 channel-last [b][y][x][16].
__global__ __launch_bounds__(256)
void convlstm_step_kernel(const float* __restrict__ x, int t,
                          const unsigned short* __restrict__ h_in,
                          unsigned short* __restrict__ h_out,
                          float* __restrict__ c_state,
                          const unsigned short* __restrict__ Wfrag,
                          const float* __restrict__ bias,
                          int first) {
    __shared__ unsigned short tile[NPX * KPAD];   // 21760 B, [px][k] bf16

    const int tid  = threadIdx.x;
    const int lane = tid & 63;
    const int wave = tid >> 6;
    const int x0 = blockIdx.x * TX;
    const int y0 = blockIdx.y * TY;
    const int bb = blockIdx.z;

    // ---- stage tile: channel-last bf16, zero-padded halo & k-pad ----
    for (int i = tid; i < NPX; i += 256) {
        int ly = i / HALO_X;
        int lx = i - ly * HALO_X;
        int gy = y0 + ly - 1;
        int gx = x0 + lx - 1;
        bool inb = (gy >= 0 && gy < HH && gx >= 0 && gx < WW);
        unsigned short* row = &tile[i * KPAD];
        if (inb && !first) {
            size_t hb = ((size_t)bb * HH * WW + (size_t)gy * WW + gx) * HIDDEN;
            *(uint4*)&row[0] = *(const uint4*)&h_in[hb];
            *(uint4*)&row[8] = *(const uint4*)&h_in[hb + 8];
        } else {
            uint4 z = {0, 0, 0, 0};
            *(uint4*)&row[0] = z;
            *(uint4*)&row[8] = z;
        }
        #pragma unroll
        for (int ci = 0; ci < CIN; ++ci) {
            float v = 0.0f;
            if (inb) v = x[(((size_t)bb * TT + t) * CIN + ci) * (size_t)(HH * WW)
                           + (size_t)gy * WW + gx];
            row[16 + ci] = f2bf(v);
        }
        row[21] = 0; row[22] = 0; row[23] = 0;
        uint4 z2 = {0, 0, 0, 0};
        *(uint4*)&row[24] = z2;
    }
    __syncthreads();

    const int u    = lane & 15;
    const int quad = lane >> 4;

    float bg[4];
    #pragma unroll
    for (int g = 0; g < 4; ++g) bg[g] = bias[g * 16 + u];

    // acc[ml][g]: 16x16 C tile, M-strip m = wave + 4*ml, N-tile = gate g.
    floatx4 acc[4][4];
    #pragma unroll
    for (int ml = 0; ml < 4; ++ml)
        #pragma unroll
        for (int g = 0; g < 4; ++g)
            acc[ml][g] = (floatx4){bg[g], bg[g], bg[g], bg[g]};

    #pragma unroll 1
    for (int tap = 0; tap < 9; ++tap) {
        int ky = tap / 3;
        int kx = tap - ky * 3;
        bf16x8 bfr[4];
        #pragma unroll
        for (int g = 0; g < 4; ++g)
            bfr[g] = *(const bf16x8*)&Wfrag[(size_t)((tap * 4 + g) * 64 + lane) * 8];
        #pragma unroll
        for (int ml = 0; ml < 4; ++ml) {
            int m  = wave + ml * 4;
            int my = m >> 1;
            int mx = (m & 1) << 4;
            int yt = my + ky;                 // halo coords (+1 pixel, -1 tap cancel)
            int xt = mx + u + kx;
            bf16x8 af = *(const bf16x8*)&tile[(yt * HALO_X + xt) * KPAD + quad * 8];
            #pragma unroll
            for (int g = 0; g < 4; ++g)
                acc[ml][g] = __builtin_amdgcn_mfma_f32_16x16x32_bf16(
                    af, bfr[g], acc[ml][g], 0, 0, 0);
        }
    }

    // ---- epilogue: gates + state update, pure per-lane (gate-major N-tiles) ----
    #pragma unroll
    for (int ml = 0; ml < 4; ++ml) {
        int m  = wave + ml * 4;
        int my = m >> 1;
        int mx = (m & 1) << 4;
        int py = y0 + my;
        #pragma unroll
        for (int r = 0; r < 4; ++r) {
            int pxx = x0 + mx + quad * 4 + r;   // C/D: row = quad*4+r, col = u
            size_t idx = ((size_t)bb * HH * WW + (size_t)py * WW + pxx) * HIDDEN + u;
            float ig = fast_sigmoid(acc[ml][0][r]);
            float fg = fast_sigmoid(acc[ml][1][r]);
            float og = fast_sigmoid(acc[ml][2][r]);
            float gg = fast_tanh(acc[ml][3][r]);
            float c_old = first ? 0.0f : c_state[idx];
            float c_new = fg * c_old + ig * gg;
            c_state[idx] = c_new;
            h_out[idx] = f2bf(og * fast_tanh(c_new));
        }
    }
}

// Final 1x1 conv from bf16 channel-last h
__global__ void final_conv_kernel(const unsigned short* __restrict__ h,
                                  const float* __restrict__ Wf,
                                  const float* __restrict__ bf_,
                                  float* __restrict__ out) {
    int i = blockIdx.x * 256 + threadIdx.x;
    if (i >= BB * HH * WW) return;
    size_t base = (size_t)i * HIDDEN;
    uint4 v0 = *(const uint4*)&h[base];
    uint4 v1 = *(const uint4*)&h[base + 8];
    const unsigned short* p0 = (const unsigned short*)&v0;
    const unsigned short* p1 = (const unsigned short*)&v1;
    float s = bf_[0];
    #pragma unroll
    for (int k = 0; k < 8; ++k) s += Wf[k] * bf2f(p0[k]);
    #pragma unroll
    for (int k = 0; k < 8; ++k) s += Wf[8 + k] * bf2f(p1[k]);
    out[i] = s;
}

extern "C" void kernel_launch(void* const* d_in, const int* in_sizes, int n_in,
                              void* d_out, int out_size, void* d_ws, size_t ws_size,
                              hipStream_t stream) {
    const float* x  = (const float*)d_in[0];
    const float* Wc = (const float*)d_in[1];
    const float* bc = (const float*)d_in[2];
    const float* Wf = (const float*)d_in[3];
    const float* bf = (const float*)d_in[4];
    float* out = (float*)d_out;

    char* ws = (char*)d_ws;
    const size_t h_bytes = (size_t)BB * HH * WW * HIDDEN * 2;   // 16.78 MB
    const size_t c_bytes = (size_t)BB * HH * WW * HIDDEN * 4;   // 33.55 MB
    unsigned short* h_a = (unsigned short*)(ws);
    unsigned short* h_b = (unsigned short*)(ws + h_bytes);
    float* c            = (float*)(ws + 2 * h_bytes);
    unsigned short* Wfr = (unsigned short*)(ws + 2 * h_bytes + c_bytes);

    prep_kernel<<<(9 * 4 * 64 * 8 + 255) / 256, 256, 0, stream>>>(Wc, Wfr);

    dim3 grid(WW / TX, HH / TY, BB);   // 8 x 32 x 8 = 2048 blocks
    dim3 block(256, 1, 1);

    const unsigned short* h_in = h_a;
    for (int t = 0; t < TT; ++t) {
        unsigned short* h_out = (t & 1) ? h_b : h_a;
        convlstm_step_kernel<<<grid, block, 0, stream>>>(
            x, t, h_in, h_out, c, Wfr, bc, (t == 0) ? 1 : 0);
        h_in = h_out;
    }

    final_conv_kernel<<<(BB * HH * WW + 255) / 256, 256, 0, stream>>>(
        h_in, Wf, bf, out);
}

// Round 4
// 691.116 us; speedup vs baseline: 3.5928x; 1.1307x over previous
//
#include <hip/hip_runtime.h>
#include <math.h>

#define HIDDEN 16
#define CIN 5
#define BB 8
#define TT 12
#define HH 256
#define WW 256
#define TX 32
#define TY 8
#define HALO_X 34
#define HALO_Y 10
#define NPX (HALO_X * HALO_Y)   // 340 staged pixels
#define STRIDE 40               // shorts per px row: 80 B = 20 banks -> conflict-free phases

typedef __attribute__((ext_vector_type(8))) short bf16x8;   // 8 bf16 (4 VGPRs)
typedef __attribute__((ext_vector_type(4))) float floatx4;

__device__ __forceinline__ unsigned short f2bf(float f) {   // RNE fp32->bf16
    unsigned int u = __float_as_uint(f);
    u += 0x7fffu + ((u >> 16) & 1u);
    return (unsigned short)(u >> 16);
}
__device__ __forceinline__ float bf2f(unsigned short s) {
    return __uint_as_float(((unsigned int)s) << 16);
}
__device__ __forceinline__ float fast_sigmoid(float x) { return 1.0f / (1.0f + __expf(-x)); }
__device__ __forceinline__ float fast_tanh(float x) {
    float e2 = __expf(-2.0f * fabsf(x));
    float t = (1.0f - e2) / (1.0f + e2);
    return copysignf(t, x);
}

// Pack W_cell [64][21][3][3] into exact B-fragment layout for
// mfma_f32_16x16x32_bf16: Wfrag[tap][gate][lane][j]; lane holds
// B[k=(lane>>4)*8+j][col=lane&15], col = hidden unit, N-tile = gate.
// k-order: 0..15 = h units (ci_ref 5+k), 16..20 = x chans, 21..31 = 0.
__global__ void prep_w_kernel(const float* __restrict__ Wc,
                              unsigned short* __restrict__ Wfrag) {
    int i = blockIdx.x * 256 + threadIdx.x;
    if (i >= 9 * 4 * 64 * 8) return;
    int j    = i & 7;
    int lane = (i >> 3) & 63;
    int g    = (i >> 9) & 3;
    int tap  = i >> 11;
    int k    = ((lane >> 4) << 3) + j;
    int col  = lane & 15;
    int o    = g * 16 + col;
    float w  = 0.0f;
    if (k < 21) {
        int ci_ref = (k < 16) ? (5 + k) : (k - 16);
        w = Wc[(o * 21 + ci_ref) * 9 + tap];
    }
    Wfrag[i] = f2bf(w);
}

// One-time x repack: planar fp32 [b][t][c][y][x] -> channel-last bf16 [b][t][y][x][8]
__global__ void prep_x_kernel(const float* __restrict__ x,
                              unsigned short* __restrict__ xp) {
    size_t n = (size_t)blockIdx.x * 256 + threadIdx.x;
    const size_t TOTPX = (size_t)BB * TT * HH * WW;
    if (n >= TOTPX) return;
    size_t bt  = n / (size_t)(HH * WW);
    size_t pix = n - bt * (size_t)(HH * WW);
    const float* src = x + bt * (size_t)CIN * HH * WW + pix;
    unsigned short v[8];
    #pragma unroll
    for (int c = 0; c < CIN; ++c) v[c] = f2bf(src[(size_t)c * HH * WW]);
    v[5] = 0; v[6] = 0; v[7] = 0;
    *(uint4*)&xp[n * 8] = *(const uint4*)v;
}

// One ConvLSTM step: implicit-GEMM conv via MFMA + fused gates/state update.
// h: bf16 channel-last [b][y][x][16]; c: fp32 channel-last [b][y][x][16].
__global__ __launch_bounds__(256, 5)
void convlstm_step_kernel(const float* __restrict__ x, int t,
                          const unsigned short* __restrict__ xp,  // may be null
                          const unsigned short* __restrict__ h_in,
                          unsigned short* __restrict__ h_out,
                          float* __restrict__ c_state,
                          const unsigned short* __restrict__ Wfrag,
                          const float* __restrict__ bias,
                          int first, int use_xp) {
    __shared__ unsigned short tile[NPX * STRIDE];   // 27200 B

    const int tid  = threadIdx.x;
    const int lane = tid & 63;
    const int wave = tid >> 6;
    const int x0 = blockIdx.x * TX;
    const int y0 = blockIdx.y * TY;
    const int bb = blockIdx.z;

    // ---- stage tile: channel-last bf16, zero-padded halo & k-pad ----
    for (int i = tid; i < NPX; i += 256) {
        int ly = i / HALO_X;
        int lx = i - ly * HALO_X;
        int gy = y0 + ly - 1;
        int gx = x0 + lx - 1;
        bool inb = (gy >= 0 && gy < HH && gx >= 0 && gx < WW);
        unsigned short* row = &tile[i * STRIDE];
        uint4 z = {0, 0, 0, 0};
        if (inb && !first) {
            size_t hb = ((size_t)bb * HH * WW + (size_t)gy * WW + gx) * HIDDEN;
            *(uint4*)&row[0] = *(const uint4*)&h_in[hb];
            *(uint4*)&row[8] = *(const uint4*)&h_in[hb + 8];
        } else {
            *(uint4*)&row[0] = z;
            *(uint4*)&row[8] = z;
        }
        if (use_xp) {
            if (inb) {
                size_t xb = (((size_t)bb * TT + t) * (size_t)(HH * WW)
                             + (size_t)gy * WW + gx) * 8;
                *(uint4*)&row[16] = *(const uint4*)&xp[xb];
            } else {
                *(uint4*)&row[16] = z;
            }
        } else {
            #pragma unroll
            for (int ci = 0; ci < CIN; ++ci) {
                float v = 0.0f;
                if (inb) v = x[(((size_t)bb * TT + t) * CIN + ci) * (size_t)(HH * WW)
                               + (size_t)gy * WW + gx];
                row[16 + ci] = f2bf(v);
            }
            row[21] = 0; row[22] = 0; row[23] = 0;
        }
        *(uint4*)&row[24] = z;
    }
    __syncthreads();

    const int u    = lane & 15;
    const int quad = lane >> 4;

    float bg[4];
    #pragma unroll
    for (int g = 0; g < 4; ++g) bg[g] = bias[g * 16 + u];

    // 2 halves of 2 M-strips each: halves the accumulator footprint (32 vs 64)
    #pragma unroll 1
    for (int half = 0; half < 2; ++half) {
        floatx4 acc[2][4];
        int abase[2];
        #pragma unroll
        for (int mh = 0; mh < 2; ++mh) {
            int ml = half * 2 + mh;
            int m  = wave + ml * 4;
            int my = m >> 1;
            int mx = (m & 1) << 4;
            abase[mh] = (my * HALO_X + mx + u) * STRIDE + quad * 8;
            #pragma unroll
            for (int g = 0; g < 4; ++g)
                acc[mh][g] = (floatx4){bg[g], bg[g], bg[g], bg[g]};
        }

        #pragma unroll 3
        for (int tap = 0; tap < 9; ++tap) {
            int ky = tap / 3;
            int kx = tap - ky * 3;
            int toff = (ky * HALO_X + kx) * STRIDE;
            bf16x8 bfr[4];
            #pragma unroll
            for (int g = 0; g < 4; ++g)
                bfr[g] = *(const bf16x8*)&Wfrag[(size_t)((tap * 4 + g) * 64 + lane) * 8];
            #pragma unroll
            for (int mh = 0; mh < 2; ++mh) {
                bf16x8 af = *(const bf16x8*)&tile[abase[mh] + toff];
                #pragma unroll
                for (int g = 0; g < 4; ++g)
                    acc[mh][g] = __builtin_amdgcn_mfma_f32_16x16x32_bf16(
                        af, bfr[g], acc[mh][g], 0, 0, 0);
            }
        }

        // ---- epilogue: gates + state update for this half's 2 strips ----
        #pragma unroll
        for (int mh = 0; mh < 2; ++mh) {
            int ml = half * 2 + mh;
            int m  = wave + ml * 4;
            int my = m >> 1;
            int mx = (m & 1) << 4;
            int py = y0 + my;
            #pragma unroll
            for (int r = 0; r < 4; ++r) {
                int pxx = x0 + mx + quad * 4 + r;
                size_t idx = ((size_t)bb * HH * WW + (size_t)py * WW + pxx) * HIDDEN + u;
                float ig = fast_sigmoid(acc[mh][0][r]);
                float fg = fast_sigmoid(acc[mh][1][r]);
                float og = fast_sigmoid(acc[mh][2][r]);
                float gg = fast_tanh(acc[mh][3][r]);
                float c_old = first ? 0.0f : c_state[idx];
                float c_new = fg * c_old + ig * gg;
                c_state[idx] = c_new;
                h_out[idx] = f2bf(og * fast_tanh(c_new));
            }
        }
    }
}

// Final 1x1 conv from bf16 channel-last h
__global__ void final_conv_kernel(const unsigned short* __restrict__ h,
                                  const float* __restrict__ Wf,
                                  const float* __restrict__ bf_,
                                  float* __restrict__ out) {
    int i = blockIdx.x * 256 + threadIdx.x;
    if (i >= BB * HH * WW) return;
    size_t base = (size_t)i * HIDDEN;
    uint4 v0 = *(const uint4*)&h[base];
    uint4 v1 = *(const uint4*)&h[base + 8];
    const unsigned short* p0 = (const unsigned short*)&v0;
    const unsigned short* p1 = (const unsigned short*)&v1;
    float s = bf_[0];
    #pragma unroll
    for (int k = 0; k < 8; ++k) s += Wf[k] * bf2f(p0[k]);
    #pragma unroll
    for (int k = 0; k < 8; ++k) s += Wf[8 + k] * bf2f(p1[k]);
    out[i] = s;
}

extern "C" void kernel_launch(void* const* d_in, const int* in_sizes, int n_in,
                              void* d_out, int out_size, void* d_ws, size_t ws_size,
                              hipStream_t stream) {
    const float* x  = (const float*)d_in[0];
    const float* Wc = (const float*)d_in[1];
    const float* bc = (const float*)d_in[2];
    const float* Wf = (const float*)d_in[3];
    const float* bf = (const float*)d_in[4];
    float* out = (float*)d_out;

    char* ws = (char*)d_ws;
    const size_t h_bytes = (size_t)BB * HH * WW * HIDDEN * 2;   // 16.78 MB
    const size_t c_bytes = (size_t)BB * HH * WW * HIDDEN * 4;   // 33.55 MB
    const size_t w_bytes = 9 * 4 * 64 * 8 * 2;                  // 36.9 KB
    const size_t x_bytes = (size_t)BB * TT * HH * WW * 8 * 2;   // 100.7 MB

    unsigned short* h_a = (unsigned short*)(ws);
    unsigned short* h_b = (unsigned short*)(ws + h_bytes);
    float* c            = (float*)(ws + 2 * h_bytes);
    unsigned short* Wfr = (unsigned short*)(ws + 2 * h_bytes + c_bytes);
    unsigned short* xp  = (unsigned short*)(ws + 2 * h_bytes + c_bytes + w_bytes);

    const int use_xp =
        (ws_size >= 2 * h_bytes + c_bytes + w_bytes + x_bytes) ? 1 : 0;

    prep_w_kernel<<<(9 * 4 * 64 * 8 + 255) / 256, 256, 0, stream>>>(Wc, Wfr);
    if (use_xp) {
        size_t totpx = (size_t)BB * TT * HH * WW;
        prep_x_kernel<<<(int)((totpx + 255) / 256), 256, 0, stream>>>(x, xp);
    }

    dim3 grid(WW / TX, HH / TY, BB);   // 2048 blocks
    dim3 block(256, 1, 1);

    const unsigned short* h_in = h_a;
    for (int t = 0; t < TT; ++t) {
        unsigned short* h_out = (t & 1) ? h_b : h_a;
        convlstm_step_kernel<<<grid, block, 0, stream>>>(
            x, t, use_xp ? xp : (const unsigned short*)0,
            h_in, h_out, c, Wfr, bc, (t == 0) ? 1 : 0, use_xp);
        h_in = h_out;
    }

    final_conv_kernel<<<(BB * HH * WW + 255) / 256, 256, 0, stream>>>(
        h_in, Wf, bf, out);
}